// Round 1
// baseline (289.957 us; speedup 1.0000x reference)
//
#include <hip/hip_runtime.h>
#include <hip/hip_bf16.h>

#define D_MSA 384
#define NHEAD 12
#define DHID  32
#define BB    2
#define NN    256
#define LL    384

struct Smem {
  float tar[D_MSA];          // target sequence row (b, l, :)
  float q[D_MSA];            // q[h*32+d], already scaled
  float wf[NHEAD][D_MSA];    // w[h][c] = sum_d q[h,d]*Wk[h*32+d,c]
  float cb[NHEAD];           // q . bk per head
  float smax[NHEAD];
  float sinv[NHEAD];
  float attn[NHEAD][NN];     // logits, transposed for reduction
};

__global__ __launch_bounds__(256, 2)
void seqw_fused(const float* __restrict__ msa,
                const float* __restrict__ Wq,
                const float* __restrict__ bq,
                const float* __restrict__ Wk,
                const float* __restrict__ bk,
                float* __restrict__ out)
{
  __shared__ Smem sm;
  const int t    = threadIdx.x;
  const int lane = t & 63;
  const int wv   = t >> 6;
  const int bl   = blockIdx.x;
  const int b    = bl / LL;
  const int l    = bl - b * LL;
  const float scale = 0.17677669529663687f; // 1/sqrt(32)

  // ---- Phase A: load tar_seq = msa[b, 0, l, :] into LDS (coalesced f4) ----
  const float* targ = msa + ((size_t)(b * NN) * LL + l) * D_MSA;
  if (t < D_MSA / 4) ((float4*)sm.tar)[t] = ((const float4*)targ)[t];
  __syncthreads();

  // ---- Phase B: q[r] = scale * (tar . Wq[r,:] + bq[r]) ----
  // lane covers c = 2*lane + 128*p, p = 0..2 (coalesced 512B Wq row reads)
  float2 t2[3];
#pragma unroll
  for (int p = 0; p < 3; ++p) t2[p] = *(const float2*)&sm.tar[2 * lane + 128 * p];
#pragma unroll 2
  for (int j = 0; j < 96; ++j) {
    const int r = wv * 96 + j;                 // wave wv owns rows [96wv, 96wv+96)
    const float* wr = Wq + (size_t)r * D_MSA;
    float s = 0.f;
#pragma unroll
    for (int p = 0; p < 3; ++p) {
      float2 w2 = *(const float2*)&wr[2 * lane + 128 * p];
      s = fmaf(t2[p].x, w2.x, s);
      s = fmaf(t2[p].y, w2.y, s);
    }
#pragma unroll
    for (int m = 32; m; m >>= 1) s += __shfl_xor(s, m);
    if (lane == 0) sm.q[r] = scale * (s + bq[r]);
  }
  __syncthreads();

  // ---- Phase C: w[h][c] = sum_d q[h*32+d] * Wk[h*32+d, c]; cb[h] = q_h . bk_h
  // thread owns column c (coalesced Wk reads across lanes; q is LDS broadcast)
#pragma unroll
  for (int pass = 0; pass < 2; ++pass) {
    const int c = t + pass * 256;
    if (c < D_MSA) {
      float a[NHEAD];
#pragma unroll
      for (int h = 0; h < NHEAD; ++h) a[h] = 0.f;
      for (int d = 0; d < DHID; ++d) {
#pragma unroll
        for (int h = 0; h < NHEAD; ++h)
          a[h] = fmaf(sm.q[h * DHID + d], Wk[(size_t)(h * DHID + d) * D_MSA + c], a[h]);
      }
#pragma unroll
      for (int h = 0; h < NHEAD; ++h) sm.wf[h][c] = a[h];
    }
  }
  if (t < NHEAD) {
    float s = 0.f;
#pragma unroll
    for (int d = 0; d < DHID; ++d) s = fmaf(sm.q[t * DHID + d], bk[t * DHID + d], s);
    sm.cb[t] = s;
  }
  __syncthreads();

  // ---- Main: thread t owns n = t; stream msa row, dot with w (LDS broadcast)
  const float* mrow = msa + ((size_t)(b * NN + t) * LL + l) * D_MSA;
  float acc[NHEAD];
#pragma unroll
  for (int h = 0; h < NHEAD; ++h) acc[h] = sm.cb[h];

  for (int c0 = 0; c0 < D_MSA; c0 += 32) {
    float4 mv[8];                        // 128B contiguous per lane (one line)
#pragma unroll
    for (int k = 0; k < 8; ++k) mv[k] = ((const float4*)(mrow + c0))[k];
#pragma unroll
    for (int h = 0; h < NHEAD; ++h) {
      float a = acc[h];
#pragma unroll
      for (int k = 0; k < 8; ++k) {
        float4 w4 = *(const float4*)&sm.wf[h][c0 + 4 * k];  // broadcast read
        a = fmaf(mv[k].x, w4.x, a);
        a = fmaf(mv[k].y, w4.y, a);
        a = fmaf(mv[k].z, w4.z, a);
        a = fmaf(mv[k].w, w4.w, a);
      }
      acc[h] = a;
    }
  }

  // ---- Softmax over n (axis=1): transpose to LDS, 64-lane butterfly reduce
#pragma unroll
  for (int h = 0; h < NHEAD; ++h) sm.attn[h][t] = acc[h];
  __syncthreads();
#pragma unroll
  for (int j = 0; j < 3; ++j) {
    const int h = wv * 3 + j;            // 4 waves x 3 heads = 12
    float v0 = sm.attn[h][lane];
    float v1 = sm.attn[h][lane + 64];
    float v2 = sm.attn[h][lane + 128];
    float v3 = sm.attn[h][lane + 192];
    float mx = fmaxf(fmaxf(v0, v1), fmaxf(v2, v3));
#pragma unroll
    for (int m = 32; m; m >>= 1) mx = fmaxf(mx, __shfl_xor(mx, m));
    float s = __expf(v0 - mx) + __expf(v1 - mx) + __expf(v2 - mx) + __expf(v3 - mx);
#pragma unroll
    for (int m = 32; m; m >>= 1) s += __shfl_xor(s, m);
    if (lane == 0) { sm.smax[h] = mx; sm.sinv[h] = 1.0f / s; }
  }
  __syncthreads();

  // ---- Write out[b, n=t, l, h] (12 floats contiguous -> 3 float4 stores)
  float o[NHEAD];
#pragma unroll
  for (int h = 0; h < NHEAD; ++h) o[h] = __expf(acc[h] - sm.smax[h]) * sm.sinv[h];
  float* ob = out + ((size_t)(b * NN + t) * LL + l) * NHEAD;
  ((float4*)ob)[0] = make_float4(o[0], o[1], o[2],  o[3]);
  ((float4*)ob)[1] = make_float4(o[4], o[5], o[6],  o[7]);
  ((float4*)ob)[2] = make_float4(o[8], o[9], o[10], o[11]);
}

extern "C" void kernel_launch(void* const* d_in, const int* in_sizes, int n_in,
                              void* d_out, int out_size, void* d_ws, size_t ws_size,
                              hipStream_t stream) {
  const float* msa = (const float*)d_in[0];
  const float* Wq  = (const float*)d_in[1];
  const float* bq  = (const float*)d_in[2];
  const float* Wk  = (const float*)d_in[3];
  const float* bk  = (const float*)d_in[4];
  float* out = (float*)d_out;

  dim3 grid(BB * LL);   // 768 blocks: one per (b, l)
  dim3 block(256);      // thread t owns n = t in the main phase
  seqw_fused<<<grid, block, 0, stream>>>(msa, Wq, bq, Wk, bk, out);
}